// Round 1
// 425.575 us; speedup vs baseline: 1.6040x; 1.6040x over previous
//
#include <hip/hip_runtime.h>

#define T_STEPS 1024
// H = F = 6, 4H = 24 gate rows, PyTorch order: i[0:6) f[6:12) g[12:18) o[18:24)
//
// Lane layout per 16-lane group (one batch element):
//   lanes 0..5  : layer0, hidden column j = lane     (computes i,f,g,o for j, owns c0_j)
//   lanes 8..13 : layer1, hidden column j = lane-8   (staggered: computes step t-1)
//   lanes 6,7,14,15: duplicate j=5 work, results unused.
// Per iteration there is exactly ONE cross-lane broadcast window (12 ds_swizzle)
// and ONE activation chain — vs 4 DS windows + 2 act chains in the previous version.

__device__ __forceinline__ float vexp2(float x) { return __builtin_amdgcn_exp2f(x); }
__device__ __forceinline__ float vrcp(float x)  { return __builtin_amdgcn_rcpf(x); }
// sigmoid(x) = rcp(1 + 2^(-x*log2e))
__device__ __forceinline__ float sigm(float x) {
    return vrcp(1.0f + vexp2(x * -1.44269504088896340736f));
}
// tanh(x) = 2*sigmoid(2x) - 1
__device__ __forceinline__ float tanh_f(float x) {
    return fmaf(2.0f, sigm(2.0f * x), -1.0f);
}

// Broadcast hv from lane ((lane & 0x10) | s) within each 32-lane half.
// BitMode ds_swizzle: src = ((lane & and) | or) ^ xor ; offset = (xor<<10)|(or<<5)|and
#define SWZ(v, s) \
    __int_as_float(__builtin_amdgcn_ds_swizzle(__float_as_int(v), (((s) << 5) | 0x10)))

// One cell step for this lane's column. A-operand = h0 broadcast (recurrent h for L0,
// input for L1). B-operand = x (L0) or h1 broadcast (L1). Split accumulators so the
// post-broadcast chain is 6 FMAs + 1 add, not 12 FMAs.
__device__ __forceinline__ float cell_step(
    const float xb[6], const float h0b[6], const float h1b[6], float& c,
    const float wai[6], const float waf[6], const float wag[6], const float wao[6],
    const float wbi[6], const float wbf[6], const float wbg[6], const float wbo[6],
    float bI, float bF, float bG, float bO, bool isL1)
{
    float bin[6];
#pragma unroll
    for (int q = 0; q < 6; ++q) bin[q] = isL1 ? h1b[q] : xb[q];

    float gI = bI, gF = bF, gG = bG, gO = bO;     // B-dot (+bias)
    float hI = 0.f, hF = 0.f, hG = 0.f, hO = 0.f; // A-dot (h0 broadcast)
#pragma unroll
    for (int q = 0; q < 6; ++q) {
        gF = fmaf(wbf[q], bin[q], gF);
        gI = fmaf(wbi[q], bin[q], gI);
        gG = fmaf(wbg[q], bin[q], gG);
        gO = fmaf(wbo[q], bin[q], gO);
        hF = fmaf(waf[q], h0b[q], hF);
        hI = fmaf(wai[q], h0b[q], hI);
        hG = fmaf(wag[q], h0b[q], hG);
        hO = fmaf(wao[q], h0b[q], hO);
    }
    // f first: it is on the c critical path; o last (needed only after tanh(c)).
    float aF = sigm(gF + hF);
    float aI = sigm(gI + hI);
    float aG = tanh_f(gG + hG);
    c = fmaf(aF, c, aI * aG);
    float aO = sigm(gO + hO);
    return aO * tanh_f(c);
}

__global__ __launch_bounds__(256) void lstm2_kernel(
    const float* __restrict__ x,
    const float* __restrict__ wih0, const float* __restrict__ whh0,
    const float* __restrict__ bih0, const float* __restrict__ bhh0,
    const float* __restrict__ wih1, const float* __restrict__ whh1,
    const float* __restrict__ bih1, const float* __restrict__ bhh1,
    float* __restrict__ out, int Btot)
{
    const int tid = threadIdx.x;
    const int grp = tid >> 4;          // 16 elements per 256-thread block
    const int l   = tid & 15;
    const int b   = blockIdx.x * 16 + grp;
    if (b >= Btot) return;             // uniform per group

    const bool isL1 = (l & 8) != 0;
    int j = l & 7; if (j > 5) j = 5;   // lanes 6,7,14,15 duplicate j=5

    // A-operand weights multiply the h0 broadcast; B-operand weights multiply (x | h1).
    const float* wa  = isL1 ? wih1 : whh0;
    const float* wb  = isL1 ? whh1 : wih0;
    const float* bip = isL1 ? bih1 : bih0;
    const float* bhp = isL1 ? bhh1 : bhh0;

    float wai[6], waf[6], wag[6], wao[6];
    float wbi[6], wbf[6], wbg[6], wbo[6];
#pragma unroll
    for (int k = 0; k < 6; ++k) {
        wai[k] = wa[(j     ) * 6 + k];
        waf[k] = wa[(6 + j ) * 6 + k];
        wag[k] = wa[(12 + j) * 6 + k];
        wao[k] = wa[(18 + j) * 6 + k];
        wbi[k] = wb[(j     ) * 6 + k];
        wbf[k] = wb[(6 + j ) * 6 + k];
        wbg[k] = wb[(12 + j) * 6 + k];
        wbo[k] = wb[(18 + j) * 6 + k];
    }
    const float bI = bip[j]      + bhp[j];
    const float bF = bip[6 + j]  + bhp[6 + j];
    const float bG = bip[12 + j] + bhp[12 + j];
    const float bO = bip[18 + j] + bhp[18 + j];

    float h0b[6], h1b[6];
#pragma unroll
    for (int k = 0; k < 6; ++k) { h0b[k] = 0.0f; h1b[k] = 0.0f; }
    float c = 0.0f;

    const float* px = x + (size_t)b * (T_STEPS * 6);
    float* ps = out + (size_t)b * (T_STEPS * 6) + (isL1 ? (l - 8) : 0);
    const bool lstore = (l >= 8) && (l < 14);

    auto loadx = [&](int t, float v[6]) {
        const float2* p2 = reinterpret_cast<const float2*>(px + (size_t)t * 6);
        float2 a = p2[0], b2 = p2[1], c2 = p2[2];
        v[0] = a.x; v[1] = a.y; v[2] = b2.x; v[3] = b2.y; v[4] = c2.x; v[5] = c2.y;
    };

    // At iter K: L0 lanes compute step K (x = CUR = x(K), h = h0b = h0(K-1));
    // L1 lanes compute step K-1 (x = h0b = h0(K-1), h = h1b = h1(K-2)).
    // Prefetch x(K+3) into PF (consumed 4 iters from now) BEFORE the step so the
    // global loads overlap ~3 iterations of compute.
#define ITER(K, CUR, PF)                                                       \
    {                                                                          \
        int tn_ = (K) + 3; if (tn_ > T_STEPS - 1) tn_ = T_STEPS - 1;           \
        loadx(tn_, PF);                                                        \
        float hv = cell_step(CUR, h0b, h1b, c, wai, waf, wag, wao,             \
                             wbi, wbf, wbg, wbo, bI, bF, bG, bO, isL1);        \
        if ((K) >= 1 && lstore) ps[(size_t)((K) - 1) * 6] = hv;                \
        h0b[0] = SWZ(hv, 0);  h0b[1] = SWZ(hv, 1);  h0b[2] = SWZ(hv, 2);       \
        h0b[3] = SWZ(hv, 3);  h0b[4] = SWZ(hv, 4);  h0b[5] = SWZ(hv, 5);       \
        h1b[0] = SWZ(hv, 8);  h1b[1] = SWZ(hv, 9);  h1b[2] = SWZ(hv, 10);      \
        h1b[3] = SWZ(hv, 11); h1b[4] = SWZ(hv, 12); h1b[5] = SWZ(hv, 13);      \
    }

    float xA[6], xB[6], xC[6], xD[6];
    loadx(0, xA); loadx(1, xB); loadx(2, xC);

    // Peel K=0: layer0 computes step 0; layer1 lanes compute garbage (inputs were 0
    // but biases make hv != 0), so reset their state afterwards.
    ITER(0, xA, xD);
    if (isL1) c = 0.0f;
#pragma unroll
    for (int k = 0; k < 6; ++k) h1b[k] = 0.0f;

    // Main: K = 1..1024 (1024 iters = 256 exact quads). At K = T the layer0 lanes
    // compute a garbage step T (clamped x) whose output is never used; layer1 lanes
    // produce the final row T-1.
    for (int k = 1; k <= T_STEPS; k += 4) {
        ITER(k,     xB, xA);
        ITER(k + 1, xC, xB);
        ITER(k + 2, xD, xC);
        ITER(k + 3, xA, xD);
    }
#undef ITER
}

extern "C" void kernel_launch(void* const* d_in, const int* in_sizes, int n_in,
                              void* d_out, int out_size, void* d_ws, size_t ws_size,
                              hipStream_t stream)
{
    const float* x    = (const float*)d_in[0];
    const float* wih0 = (const float*)d_in[1];
    const float* whh0 = (const float*)d_in[2];
    const float* bih0 = (const float*)d_in[3];
    const float* bhh0 = (const float*)d_in[4];
    const float* wih1 = (const float*)d_in[5];
    const float* whh1 = (const float*)d_in[6];
    const float* bih1 = (const float*)d_in[7];
    const float* bhh1 = (const float*)d_in[8];
    float* out = (float*)d_out;

    const int Btot   = in_sizes[0] / (T_STEPS * 6);
    const int blocks = (Btot + 15) / 16;
    hipLaunchKernelGGL(lstm2_kernel, dim3(blocks), dim3(256), 0, stream,
                       x, wih0, whh0, bih0, bhh0, wih1, whh1, bih1, bhh1, out, Btot);
}